// Round 6
// baseline (123.257 us; speedup 1.0000x reference)
//
#include <hip/hip_runtime.h>

// SO3SelfInteraction: y[a,k,f] = sum_e Wcg[e] * x[a,i1[e],f] * x[a,i2[e],f]
// LMAX=2 -> S=9, N_ATOMS=32000, N_FEAT=128.
//
// R5 change vs R4: SINGLE fused kernel. Each block redundantly builds the
// merged pair-major weight table W[45][12] in LDS (deterministic: <=2
// commutative fp adds per cell via LDS atomics), removing the prep kernel
// launch + graph-dependency stall (~5us while 255 CUs idle). Weights are
// consumed via broadcast ds_read_b128 (uniform address, conflict-free).
// Store path back to plain nontemporal builtin (R4 proved sc0/sc1/nt asm
// does not change MALL allocation: FETCH stayed 72MB).

#define S9 9
#define NFEAT 128
#define THREADS 256
#define NPAIR 45
#define WSTRIDE 12   // padded floats per pair row (48 B -> 3x b128 reads)

typedef float f4 __attribute__((ext_vector_type(4)));

__global__ __launch_bounds__(THREADS, 8) void so3_fused_kernel(
        const float* __restrict__ x,
        const float* __restrict__ weight,
        const float* __restrict__ cg_vals,
        const int* __restrict__ idx_1,
        const int* __restrict__ idx_2,
        const int* __restrict__ idx_out,
        const int* __restrict__ widx_1,
        const int* __restrict__ widx_2,
        int nnz,
        float* __restrict__ y) {
    __shared__ __align__(16) float Wlds[NPAIR * WSTRIDE];

    const int tid = threadIdx.x;

    // ---- per-block prep: build merged weight table in LDS ----
    #pragma unroll
    for (int i = tid; i < NPAIR * WSTRIDE; i += THREADS) Wlds[i] = 0.f;
    __syncthreads();

    for (int e = tid; e < nnz; e += THREADS) {
        const int i = idx_1[e];
        const int j = idx_2[e];
        const int k = idx_out[e];
        const float w = weight[widx_1[e] * 3 + widx_2[e]] * cg_vals[e];
        const int a = min(i, j);
        const int b = max(i, j);
        const int p = a * 9 - a * (a - 1) / 2 + (b - a);
        // <=2 adds per cell ((i,j),(j,i)); fp add commutative -> deterministic
        atomicAdd(&Wlds[p * WSTRIDE + k], w);
    }
    __syncthreads();

    // ---- main compute: register-resident x rows, unrolled 45 pairs ----
    static constexpr int PA[NPAIR] = {
        0,0,0,0,0,0,0,0,0, 1,1,1,1,1,1,1,1, 2,2,2,2,2,2,2,
        3,3,3,3,3,3, 4,4,4,4,4, 5,5,5,5, 6,6,6, 7,7, 8};
    static constexpr int PB[NPAIR] = {
        0,1,2,3,4,5,6,7,8, 1,2,3,4,5,6,7,8, 2,3,4,5,6,7,8,
        3,4,5,6,7,8, 4,5,6,7,8, 5,6,7,8, 6,7,8, 7,8, 8};

    const int gid  = blockIdx.x * THREADS + tid;
    const int atom = gid >> 5;
    const int c4   = gid & 31;
    const size_t base = (size_t)atom * (S9 * NFEAT) + (size_t)c4 * 4;

    f4 xv[S9];
    #pragma unroll
    for (int s = 0; s < S9; ++s)
        xv[s] = *(const f4*)(x + base + (size_t)s * NFEAT);

    f4 acc[S9];
    #pragma unroll
    for (int k = 0; k < S9; ++k) acc[k] = (f4)0.f;

    #pragma unroll
    for (int p = 0; p < NPAIR; ++p) {
        // uniform-address LDS reads: broadcast, conflict-free
        const f4 wA = *(const f4*)(&Wlds[p * WSTRIDE]);      // k = 0..3
        const f4 wB = *(const f4*)(&Wlds[p * WSTRIDE + 4]);  // k = 4..7
        const f4 wC = *(const f4*)(&Wlds[p * WSTRIDE + 8]);  // k = 8 (+pad)
        const f4 prod = xv[PA[p]] * xv[PB[p]];
        acc[0] = acc[0] + wA[0] * prod;
        acc[1] = acc[1] + wA[1] * prod;
        acc[2] = acc[2] + wA[2] * prod;
        acc[3] = acc[3] + wA[3] * prod;
        acc[4] = acc[4] + wB[0] * prod;
        acc[5] = acc[5] + wB[1] * prod;
        acc[6] = acc[6] + wB[2] * prod;
        acc[7] = acc[7] + wB[3] * prod;
        acc[8] = acc[8] + wC[0] * prod;
    }

    #pragma unroll
    for (int k = 0; k < S9; ++k)
        __builtin_nontemporal_store(acc[k], (f4*)(y + base + (size_t)k * NFEAT));
}

extern "C" void kernel_launch(void* const* d_in, const int* in_sizes, int n_in,
                              void* d_out, int out_size, void* d_ws, size_t ws_size,
                              hipStream_t stream) {
    const float* x       = (const float*)d_in[0];
    const float* weight  = (const float*)d_in[1];
    const float* cg_vals = (const float*)d_in[2];
    const int* idx_1     = (const int*)d_in[3];
    const int* idx_2     = (const int*)d_in[4];
    const int* idx_out   = (const int*)d_in[5];
    const int* widx_1    = (const int*)d_in[6];
    const int* widx_2    = (const int*)d_in[7];
    float* y             = (float*)d_out;

    const int nnz     = in_sizes[2];
    const int n_atoms = in_sizes[0] / (S9 * NFEAT);       // 32000

    const int total = n_atoms * 32;                        // one thread per (atom, f4)
    so3_fused_kernel<<<total / THREADS, THREADS, 0, stream>>>(
        x, weight, cg_vals, idx_1, idx_2, idx_out, widx_1, widx_2, nnz, y);
}

// Round 7
// 70.154 us; speedup vs baseline: 1.7570x; 1.7570x over previous
//
#include <hip/hip_runtime.h>

// SO3SelfInteraction: y[a,k,f] = sum_e Wcg[e] * x[a,i1[e],f] * x[a,i2[e],f]
// LMAX=2 -> S=9, N_ATOMS=32000, N_FEAT=128.
//
// R6 vs R5: REVERT the fused single-kernel (high concurrency thrashed MALL:
// FETCH 72->227MB, WRITE 144->311MB). Back to R3's two-kernel structure, with
// one experiment: 2 chunks per thread, all 18 x-loads issued up-front so
// chunk B's HBM latency hides under chunk A's FMA chain (tests latency- vs
// saturation-bound). Plain stores (nt proven neutral at low concurrency).

#define S9 9
#define NFEAT 128
#define THREADS 256
#define NPAIR 45
#define WSTRIDE 12   // padded floats per pair row

typedef float f4 __attribute__((ext_vector_type(4)));

// d_ws layout: W[45][12] floats (pair-major, zero-padded).

__global__ void so3_prep_kernel(const float* __restrict__ weight,
                                const float* __restrict__ cg_vals,
                                const int* __restrict__ idx_1,
                                const int* __restrict__ idx_2,
                                const int* __restrict__ idx_out,
                                const int* __restrict__ widx_1,
                                const int* __restrict__ widx_2,
                                int nnz, float* __restrict__ W) {
    __shared__ float d[NPAIR * WSTRIDE];
    const int tid = threadIdx.x;

    for (int i = tid; i < NPAIR * WSTRIDE; i += THREADS) d[i] = 0.f;
    __syncthreads();

    for (int e = tid; e < nnz; e += THREADS) {
        const int i = idx_1[e];
        const int j = idx_2[e];
        const int k = idx_out[e];
        const float w = weight[widx_1[e] * 3 + widx_2[e]] * cg_vals[e];
        const int a = min(i, j);
        const int b = max(i, j);
        const int p = a * 9 - a * (a - 1) / 2 + (b - a);
        // <=2 adds per cell ((i,j),(j,i)); fp add commutative -> deterministic
        atomicAdd(&d[p * WSTRIDE + k], w);
    }
    __syncthreads();

    for (int i = tid; i < NPAIR * WSTRIDE; i += THREADS) W[i] = d[i];
}

__device__ __forceinline__ void so3_compute(const f4 xv[S9],
                                            const float* __restrict__ W,
                                            f4 acc[S9]) {
    static constexpr int PA[NPAIR] = {
        0,0,0,0,0,0,0,0,0, 1,1,1,1,1,1,1,1, 2,2,2,2,2,2,2,
        3,3,3,3,3,3, 4,4,4,4,4, 5,5,5,5, 6,6,6, 7,7, 8};
    static constexpr int PB[NPAIR] = {
        0,1,2,3,4,5,6,7,8, 1,2,3,4,5,6,7,8, 2,3,4,5,6,7,8,
        3,4,5,6,7,8, 4,5,6,7,8, 5,6,7,8, 6,7,8, 7,8, 8};
    #pragma unroll
    for (int k = 0; k < S9; ++k) acc[k] = (f4)0.f;
    #pragma unroll
    for (int p = 0; p < NPAIR; ++p) {
        const f4 wA = *(const f4*)(W + p * WSTRIDE);       // k = 0..3
        const f4 wB = *(const f4*)(W + p * WSTRIDE + 4);   // k = 4..7
        const f4 wC = *(const f4*)(W + p * WSTRIDE + 8);   // k = 8 (+pad)
        const f4 prod = xv[PA[p]] * xv[PB[p]];
        acc[0] = acc[0] + wA[0] * prod;
        acc[1] = acc[1] + wA[1] * prod;
        acc[2] = acc[2] + wA[2] * prod;
        acc[3] = acc[3] + wA[3] * prod;
        acc[4] = acc[4] + wB[0] * prod;
        acc[5] = acc[5] + wB[1] * prod;
        acc[6] = acc[6] + wB[2] * prod;
        acc[7] = acc[7] + wB[3] * prod;
        acc[8] = acc[8] + wC[0] * prod;
    }
}

__global__ __launch_bounds__(THREADS) void so3_main_kernel(
        const float* __restrict__ x,
        const float* __restrict__ W,
        float* __restrict__ y,
        int total_threads) {
    const int g = blockIdx.x * THREADS + threadIdx.x;

    // chunk A = g, chunk B = g + total_threads (each chunk = one (atom, f4))
    const int atomA = g >> 5,                 c4A = g & 31;
    const int gB    = g + total_threads;
    const int atomB = gB >> 5,                c4B = gB & 31;
    const size_t baseA = (size_t)atomA * (S9 * NFEAT) + (size_t)c4A * 4;
    const size_t baseB = (size_t)atomB * (S9 * NFEAT) + (size_t)c4B * 4;

    // issue ALL 18 loads up-front: chunk B's latency hides under A's compute
    f4 xvA[S9], xvB[S9];
    #pragma unroll
    for (int s = 0; s < S9; ++s)
        xvA[s] = *(const f4*)(x + baseA + (size_t)s * NFEAT);
    #pragma unroll
    for (int s = 0; s < S9; ++s)
        xvB[s] = *(const f4*)(x + baseB + (size_t)s * NFEAT);

    f4 acc[S9];
    so3_compute(xvA, W, acc);
    #pragma unroll
    for (int k = 0; k < S9; ++k)
        *(f4*)(y + baseA + (size_t)k * NFEAT) = acc[k];

    so3_compute(xvB, W, acc);
    #pragma unroll
    for (int k = 0; k < S9; ++k)
        *(f4*)(y + baseB + (size_t)k * NFEAT) = acc[k];
}

extern "C" void kernel_launch(void* const* d_in, const int* in_sizes, int n_in,
                              void* d_out, int out_size, void* d_ws, size_t ws_size,
                              hipStream_t stream) {
    const float* x       = (const float*)d_in[0];
    const float* weight  = (const float*)d_in[1];
    const float* cg_vals = (const float*)d_in[2];
    const int* idx_1     = (const int*)d_in[3];
    const int* idx_2     = (const int*)d_in[4];
    const int* idx_out   = (const int*)d_in[5];
    const int* widx_1    = (const int*)d_in[6];
    const int* widx_2    = (const int*)d_in[7];
    float* y             = (float*)d_out;
    float* W             = (float*)d_ws;

    const int nnz     = in_sizes[2];
    const int n_atoms = in_sizes[0] / (S9 * NFEAT);       // 32000

    so3_prep_kernel<<<1, THREADS, 0, stream>>>(weight, cg_vals, idx_1, idx_2,
                                               idx_out, widx_1, widx_2, nnz, W);

    const int total_chunks  = n_atoms * 32;                // 1,024,000
    const int total_threads = total_chunks / 2;            // 2 chunks/thread
    so3_main_kernel<<<total_threads / THREADS, THREADS, 0, stream>>>(
        x, W, y, total_threads);
}